// Round 15
// baseline (822.970 us; speedup 1.0000x reference)
//
#include <hip/hip_runtime.h>
#include <hip/hip_bf16.h>

// ---------- types ----------
typedef _Float16 h16;
typedef h16   h16x8 __attribute__((ext_vector_type(8)));
typedef h16   h16x4 __attribute__((ext_vector_type(4)));
typedef float f32x4 __attribute__((ext_vector_type(4)));

#define EMB 1024
#define ED4 4096L   // EMB*4 flattened feature dim

// ---------- async global->LDS (16B per lane, wave-uniform LDS base) ----------
__device__ __forceinline__ void gload_lds16(const void* g, void* l) {
    __builtin_amdgcn_global_load_lds(
        (__attribute__((address_space(1))) void*)g,
        (__attribute__((address_space(3))) void*)l,
        16, 0, 0);
}

// ---------- build effective block weight M[o*4+q][i*4+c] = s(q,c)*W[q^c][o][i], fp16 ----------
__global__ __launch_bounds__(256) void k_build_m(const float* __restrict__ W, h16* __restrict__ M) {
    int t = blockIdx.x * 256 + threadIdx.x;   // [0, 4096*1024)
    int i = t & 1023;
    int n = t >> 10;          // o*4+q
    int o = n >> 2, q = n & 3;
    // sign masks per q (bit c set => negative): q0:0xE q1:0x8 q2:0x2 q3:0x4
    unsigned packed = 0xEu | (0x8u << 4) | (0x2u << 8) | (0x4u << 12);
    unsigned sm = (packed >> (q * 4)) & 0xFu;
    h16x4 out;
#pragma unroll
    for (int c = 0; c < 4; ++c) {
        int d = q ^ c;
        float w = W[((long)d * EMB + o) * EMB + i];
        out[c] = (h16)(((sm >> c) & 1u) ? -w : w);
    }
    *(h16x4*)&M[(long)n * ED4 + i * 4] = out;
}

// ---------- fp32 -> fp16 convert (x inputs), 4 elems/thread ----------
__global__ __launch_bounds__(256) void k_f32_to_f16(const float* __restrict__ in, h16* __restrict__ out) {
    long i = ((long)blockIdx.x * 256 + threadIdx.x) * 4;
    float4 v = *(const float4*)(in + i);
    h16x4 o;
    o[0] = (h16)v.x; o[1] = (h16)v.y; o[2] = (h16)v.z; o[3] = (h16)v.w;
    *(h16x4*)(out + i) = o;
}

// =====================================================================
// 256x256-tile, BK=32, 2-phase GEMM — r15: BK 64->32 so LDS drops to
// 64 KiB -> 2 blocks/CU (16 waves) for cross-block bubble-filling.
// Same 2-phase relaxed-barrier structure as r13/r14 green.
// LDS: h16 lds[2 buf][2 mat][8192] = 64 KiB. Buffer cb=(t&1)*16384;
// A at cb (half h: +h*4096), B at cb+8192. Row r: 32 h16, 4 16B-slots.
// Swizzle (r9-verified involution): LDS(r, s) holds global slot
// s ^ ((r>>1)&3); store via pre-swizzled global col (linear LDS dest),
// read koff = (kq ^ ((fr>>1)&3))*8. Bank-uniform: 64 lanes -> 8
// words/bank exactly.
// STAGE = ONE gload line (512 thr x 16B = 8 KB = one 128-row half).
// Ledger: phA(t) reads A0,B0,B1, stages (t+1).A1,B1 [other buffer;
// prev contents last read phB(t-1)/phA(t-1), >=1 barrier behind];
// MFMA (0,0)(0,1); BAR. phB(t) reads A1, stages (t+2).A0,B0 [same
// buffer, disjoint from A1; prev contents last read phA(t), 1 barrier
// behind]; vmcnt(2) leaves exactly the 2 newest ((t+2).A0,B0) ->
// everything tile t+1 reads (older) has landed; MFMA (1,0)(1,1); BAR.
// Prologue: t0 all 4 halves + t1.{A0,B0} = 6 lines, vmcnt(2) -> t0
// landed. vmcnt(0) at t >= nt-2. Readers drain own lgkm at MFMA
// consumption before each post-barrier (compiler-counted waits).
// VT=true: V-projection epilogue writes Vt[(b*16+h)][f][t] directly.
// =====================================================================
#define BAR() __builtin_amdgcn_s_barrier()
#define STAGE(matv, basev, row0v, ldv, tt, hh) do { \
    const h16* _src = (basev) + ((row0v) + (hh) * 128L) * (ldv) + (long)(tt) * 32 + scol; \
    h16* _dst = &lds[(((tt) & 1) << 14) + (matv) * 8192 + (hh) * 4096 + w * 512]; \
    gload_lds16(_src, _dst); \
} while (0)
#define LDA_(mh, m) (*(const h16x8*)&lds[cb + (mh) * 4096 + (wm * 64 + (m) * 16 + fr) * 32 + koff])
#define LDB_(nh, n) (*(const h16x8*)&lds[cb + 8192 + (nh) * 4096 + (wn * 32 + (n) * 16 + fr) * 32 + koff])
#define MFMA_Q(MH, NH, BF) do { \
    __builtin_amdgcn_s_setprio(1); \
    _Pragma("unroll") \
    for (int m = 0; m < 4; ++m) \
        _Pragma("unroll") \
        for (int n = 0; n < 2; ++n) \
            acc[MH][NH][m][n] = __builtin_amdgcn_mfma_f32_16x16x32_f16(af[m], BF[n], acc[MH][NH][m][n], 0, 0, 0); \
    __builtin_amdgcn_s_setprio(0); \
} while (0)

template <typename OUT_T, bool VT, bool HAS_BIAS>
__global__ __launch_bounds__(512, 2) void k_gemm256(
    const h16* __restrict__ A, const h16* __restrict__ B,
    OUT_T* __restrict__ C, const float* __restrict__ bias,
    int lda, int ldb, int ldc,
    long sAb, long sAh, long sBb, long sBh, long sCb, long sCh,
    float alpha, int nt)
{
    __shared__ __align__(16) h16 lds[32768];   // 64 KiB -> 2 blocks/CU

    const int tid = threadIdx.x;
    const int w  = tid >> 6, l = tid & 63;
    const int wm = w >> 2, wn = w & 3;          // wave grid 2x4 within each quadrant
    const int fr = l & 15, kq = l >> 4;
    const int koff = ((kq ^ ((fr >> 1) & 3)) << 3);

    const int z = blockIdx.z, zb = z >> 4, zh = z & 15;
    const h16* Ab = A + zb * sAb + zh * sAh;
    const h16* Bb = B + zb * sBb + zh * sBh;

    // staging: thread covers 16B; srow in [0,128) per gload line; swizzled col
    const int srow = tid >> 2;
    const int scol = (((tid & 3) ^ ((tid >> 3) & 3)) << 3);
    const long arow0 = (long)blockIdx.x * 256 + srow;
    const long brow0 = (long)blockIdx.y * 256 + srow;

    f32x4 acc[2][2][4][2] = {};   // [mh][nh][m][n]

    // prologue: t0.{A0,B0,A1,B1} + t1.{A0,B0} (6 lines); vmcnt(2) -> t0 landed
    STAGE(0, Ab, arow0, lda, 0, 0);
    STAGE(1, Bb, brow0, ldb, 0, 0);
    STAGE(0, Ab, arow0, lda, 0, 1);
    STAGE(1, Bb, brow0, ldb, 0, 1);
    STAGE(0, Ab, arow0, lda, 1, 0);
    STAGE(1, Bb, brow0, ldb, 1, 0);
    asm volatile("s_waitcnt vmcnt(2)" ::: "memory");
    __builtin_amdgcn_sched_barrier(0);
    BAR();

    for (int t = 0; t < nt; ++t) {
        const int cb = (t & 1) << 14;
        h16x8 af[4], b0[2], b1[2];

        // ---- phase A: quadrants (0,0)+(0,1) — read A0,B0,B1; stage (t+1).A1,B1 ----
#pragma unroll
        for (int m = 0; m < 4; ++m) af[m] = LDA_(0, m);
#pragma unroll
        for (int n = 0; n < 2; ++n) b0[n] = LDB_(0, n);
#pragma unroll
        for (int n = 0; n < 2; ++n) b1[n] = LDB_(1, n);
        if (t + 1 < nt) {
            STAGE(0, Ab, arow0, lda, t + 1, 1);
            STAGE(1, Bb, brow0, ldb, t + 1, 1);
        }
        MFMA_Q(0, 0, b0);
        MFMA_Q(0, 1, b1);
        BAR();

        // ---- phase B: quadrants (1,0)+(1,1) — read A1; stage (t+2).A0,B0; drain ----
#pragma unroll
        for (int m = 0; m < 4; ++m) af[m] = LDA_(1, m);
        if (t + 2 < nt) {
            STAGE(0, Ab, arow0, lda, t + 2, 0);
            STAGE(1, Bb, brow0, ldb, t + 2, 0);
        }
        if (t < nt - 2) { asm volatile("s_waitcnt vmcnt(2)" ::: "memory"); }
        else            { asm volatile("s_waitcnt vmcnt(0)" ::: "memory"); }
        __builtin_amdgcn_sched_barrier(0);
        MFMA_Q(1, 0, b0);
        MFMA_Q(1, 1, b1);
        BAR();
    }

    // epilogue: row = bx*256 + mh*128 + wm*64 + m*16 + kq*4 + j
    //           col = by*256 + nh*128 + wn*32 + n*16 + fr
    OUT_T* Cb = C + zb * sCb + zh * sCh;
    const long row00 = (long)blockIdx.x * 256 + wm * 64 + kq * 4;
    const int  col00 = (int)blockIdx.y * 256 + wn * 32 + fr;
#pragma unroll
    for (int mh = 0; mh < 2; ++mh)
#pragma unroll
        for (int nh = 0; nh < 2; ++nh)
#pragma unroll
            for (int n = 0; n < 2; ++n) {
                const int col = col00 + nh * 128 + n * 16;
                const float bv = HAS_BIAS ? bias[col] : 0.0f;
#pragma unroll
                for (int m = 0; m < 4; ++m) {
                    const long r0 = row00 + mh * 128 + m * 16;
                    if constexpr (VT) {
                        // Vt[(r>>10)*16 + (col>>8)][col&255][r&1023], r0 % 4 == 0
                        h16x4 o;
#pragma unroll
                        for (int j = 0; j < 4; ++j) o[j] = (h16)(acc[mh][nh][m][n][j] * alpha + bv);
                        const long zidx = (r0 >> 10) * 16 + (col >> 8);
                        *(h16x4*)((h16*)Cb + zidx * 262144L + (long)(col & 255) * 1024 + (r0 & 1023)) = o;
                    } else {
#pragma unroll
                        for (int j = 0; j < 4; ++j)
                            Cb[(r0 + j) * (long)ldc + col] = (OUT_T)(acc[mh][nh][m][n][j] * alpha + bv);
                    }
                }
            }
}

// ---------- GEMM: C[m][n] = alpha * sum_k A[m][k]*B[n][k] (+ bias[n]) ----------
// 128x128 tile, BK=32 (m97 structure) — used for the attention PV GEMM.
// LDS XOR-swizzle (r9): LDS row r holds global 16B-slot s at slot s ^ ((r>>1)&3).
template <typename OUT_T, bool HAS_BIAS>
__global__ __launch_bounds__(256) void k_gemm_bt(
    const h16* __restrict__ A, const h16* __restrict__ B,
    OUT_T* __restrict__ C, const float* __restrict__ bias,
    int lda, int ldb, int ldc,
    long sAb, long sAh, long sBb, long sBh, long sCb, long sCh,
    float alpha, int kIters)
{
    __shared__ __align__(16) h16 As[128 * 32];
    __shared__ __align__(16) h16 Bs[128 * 32];

    const int z = blockIdx.z, zb = z >> 4, zh = z & 15;
    const h16* Ab = A + zb * sAb + zh * sAh + (long)blockIdx.x * 128 * lda;
    const h16* Bb = B + zb * sBb + zh * sBh + (long)blockIdx.y * 128 * ldb;

    const int tid = threadIdx.x, w = tid >> 6, lane = tid & 63;
    const int wr = (w >> 1) * 64, wc = (w & 1) * 64;
    const int scol = (((lane & 3) ^ ((lane >> 3) & 3)) * 8);   // swizzled global src slot
    const int srow = lane >> 2;
    const int fr   = lane & 15;
    const int koff = (((lane >> 4) ^ ((fr >> 1) & 3)) * 8);    // swizzled LDS read slot

    f32x4 acc[4][4] = {};

    for (int kt = 0; kt < kIters; ++kt) {
        const int k0 = kt * 32;
#pragma unroll
        for (int j = 0; j < 2; ++j) {
            const int ca  = w * 2 + j;
            const int row = ca * 16 + srow;
            gload_lds16(Ab + (long)row * lda + k0 + scol, &As[ca * 512]);
            gload_lds16(Bb + (long)row * ldb + k0 + scol, &Bs[ca * 512]);
        }
        __syncthreads();

        h16x8 af[4], bfr[4];
#pragma unroll
        for (int m = 0; m < 4; ++m)
            af[m] = *(const h16x8*)&As[(wr + m * 16 + fr) * 32 + koff];
#pragma unroll
        for (int n = 0; n < 4; ++n)
            bfr[n] = *(const h16x8*)&Bs[(wc + n * 16 + fr) * 32 + koff];
        __syncthreads();

#pragma unroll
        for (int m = 0; m < 4; ++m)
#pragma unroll
            for (int n = 0; n < 4; ++n)
                acc[m][n] = __builtin_amdgcn_mfma_f32_16x16x32_f16(af[m], bfr[n], acc[m][n], 0, 0, 0);
    }

    OUT_T* Cb = C + zb * sCb + zh * sCh;
    const long rbase = (long)blockIdx.x * 128 + wr + (lane >> 4) * 4;
    const int  cbase = blockIdx.y * 128 + wc + fr;
#pragma unroll
    for (int n = 0; n < 4; ++n) {
        const int col = cbase + n * 16;
        const float bv = HAS_BIAS ? bias[col] : 0.0f;
#pragma unroll
        for (int m = 0; m < 4; ++m) {
            const long row0 = rbase + m * 16;
#pragma unroll
            for (int j = 0; j < 4; ++j) {
                float vv = acc[m][n][j] * alpha + bv;
                Cb[(row0 + j) * ldc + col] = (OUT_T)vv;
            }
        }
    }
}

// ---------- row softmax over S[row][1024] fp16 in place ----------
__global__ __launch_bounds__(256) void k_softmax(h16* __restrict__ S) {
    const long row = blockIdx.x;
    h16* p = S + row * 1024;
    const int tid = threadIdx.x, w = tid >> 6, lane = tid & 63;
    h16x4 xi = *(const h16x4*)&p[tid * 4];
    float x[4];
#pragma unroll
    for (int j = 0; j < 4; ++j) x[j] = (float)xi[j];
    float m = fmaxf(fmaxf(x[0], x[1]), fmaxf(x[2], x[3]));
#pragma unroll
    for (int off = 32; off; off >>= 1) m = fmaxf(m, __shfl_xor(m, off));
    __shared__ float red[8];
    if (lane == 0) red[w] = m;
    __syncthreads();
    m = fmaxf(fmaxf(red[0], red[1]), fmaxf(red[2], red[3]));
    float s = 0.0f;
#pragma unroll
    for (int j = 0; j < 4; ++j) { x[j] = __expf(x[j] - m); s += x[j]; }
#pragma unroll
    for (int off = 32; off; off >>= 1) s += __shfl_xor(s, off);
    if (lane == 0) red[4 + w] = s;
    __syncthreads();
    s = red[4] + red[5] + red[6] + red[7];
    const float inv = 1.0f / s;
    h16x4 o;
#pragma unroll
    for (int j = 0; j < 4; ++j) o[j] = (h16)(x[j] * inv);
    *(h16x4*)&p[tid * 4] = o;
}

// ---------- launch ----------
extern "C" void kernel_launch(void* const* d_in, const int* in_sizes, int n_in,
                              void* d_out, int out_size, void* d_ws, size_t ws_size,
                              hipStream_t stream) {
    const float* q  = (const float*)d_in[0];
    const float* k  = (const float*)d_in[1];
    const float* v  = (const float*)d_in[2];
    const float* Wq = (const float*)d_in[3];
    const float* bq = (const float*)d_in[4];
    const float* Wk = (const float*)d_in[5];
    const float* bk = (const float*)d_in[6];
    const float* Wv = (const float*)d_in[7];
    const float* bv = (const float*)d_in[8];
    const float* Wo = (const float*)d_in[9];
    const float* bo = (const float*)d_in[10];
    float* out = (float*)d_out;

    // workspace: 256 MB exactly (proven budget; 320 MB faulted in r12).
    // Sc is 64 MB -> attention chunked as 2 x 32-z batches.
    char* ws = (char*)d_ws;
    const long MB = 1024L * 1024;
    h16* X  = (h16*)(ws + 0 * MB);     // 32 MB: converted q/k/v input (serial)
    h16* M  = (h16*)(ws + 32 * MB);    // 32 MB: effective weight (serial)
    h16* Qb = (h16*)(ws + 64 * MB);
    h16* Kb = (h16*)(ws + 96 * MB);
    h16* Vt = (h16*)(ws + 128 * MB);   // Vt[64 z][256 f][1024 t]
    h16* AO = (h16*)(ws + 160 * MB);
    h16* Sc = (h16*)(ws + 192 * MB);   // 64 MB score chunk (2 batches, 32 heads)

    dim3 blk(256);
    dim3 g256(16, 16, 1);

    // Q projection: convert, build weight, GEMM (serially reusing X, M)
    k_f32_to_f16<<<16384, blk, 0, stream>>>(q, X);
    k_build_m<<<16384, blk, 0, stream>>>(Wq, M);
    k_gemm256<h16, false, true><<<g256, 512, 0, stream>>>(
        X, M, Qb, bq, 4096, 4096, 4096, 0, 0, 0, 0, 0, 0, 1.0f, 128);

    // K projection
    k_f32_to_f16<<<16384, blk, 0, stream>>>(k, X);
    k_build_m<<<16384, blk, 0, stream>>>(Wk, M);
    k_gemm256<h16, false, true><<<g256, 512, 0, stream>>>(
        X, M, Kb, bk, 4096, 4096, 4096, 0, 0, 0, 0, 0, 0, 1.0f, 128);

    // V projection (epilogue writes transposed Vt directly)
    k_f32_to_f16<<<16384, blk, 0, stream>>>(v, X);
    k_build_m<<<16384, blk, 0, stream>>>(Wv, M);
    k_gemm256<h16, true, true><<<g256, 512, 0, stream>>>(
        X, M, Vt, bv, 4096, 4096, 4096, 0, 0, 0, 0, 0, 0, 1.0f, 128);

    // attention: 2 chunks of 32 z (= 2 batches x 16 heads) through 64 MB Sc
    for (int c = 0; c < 2; ++c) {
        const h16* Qc  = Qb + (long)c * 2 * 1024 * 4096;
        const h16* Kc  = Kb + (long)c * 2 * 1024 * 4096;
        const h16* VtC = Vt + (long)c * 32 * 262144;
        h16*       AOc = AO + (long)c * 2 * 1024 * 4096;

        // scores: Sc[z][1024][1024] = (Q K^T)/16, fp16 — 256^2-tile kernel, nt=8
        k_gemm256<h16, false, false><<<dim3(4, 4, 32), 512, 0, stream>>>(
            Qc, Kc, Sc, nullptr,
            4096, 4096, 1024,
            1024L * 4096, 256,                    // A: zb (batch), zh (head) strides
            1024L * 4096, 256,                    // B
            16L * 1024 * 1024, 1024L * 1024,      // C
            0.0625f, 8);

        // softmax rows in place (fp16): 32 z x 1024 rows
        k_softmax<<<32768, blk, 0, stream>>>(Sc);

        // attn out: AOc[t][h*256+f] = P_z . Vt_z^T  (512 blocks = 2/CU)
        k_gemm_bt<h16, false><<<dim3(8, 2, 32), blk, 0, stream>>>(
            Sc, VtC, AOc, nullptr,
            1024, 1024, 4096,
            16L * 1024 * 1024, 1024L * 1024,      // A
            16L * 262144, 262144,                 // B
            1024L * 4096, 256,                    // C
            1.0f, 32);
    }

    // output projection: out = AO . Mo^T + bo (fp32 out)
    k_build_m<<<16384, blk, 0, stream>>>(Wo, M);
    k_gemm256<float, false, true><<<g256, 512, 0, stream>>>(
        AO, M, out, bo, 4096, 4096, 4096, 0, 0, 0, 0, 0, 0, 1.0f, 128);
}

// Round 16
// 802.036 us; speedup vs baseline: 1.0261x; 1.0261x over previous
//
#include <hip/hip_runtime.h>
#include <hip/hip_bf16.h>

// ---------- types ----------
typedef _Float16 h16;
typedef h16   h16x8 __attribute__((ext_vector_type(8)));
typedef h16   h16x4 __attribute__((ext_vector_type(4)));
typedef float f32x4 __attribute__((ext_vector_type(4)));

#define EMB 1024
#define ED4 4096L   // EMB*4 flattened feature dim

// ---------- async global->LDS (16B per lane, wave-uniform LDS base) ----------
__device__ __forceinline__ void gload_lds16(const void* g, void* l) {
    __builtin_amdgcn_global_load_lds(
        (__attribute__((address_space(1))) void*)g,
        (__attribute__((address_space(3))) void*)l,
        16, 0, 0);
}

// ---------- build effective block weight M[o*4+q][i*4+c] = s(q,c)*W[q^c][o][i], fp16 ----------
__global__ __launch_bounds__(256) void k_build_m(const float* __restrict__ W, h16* __restrict__ M) {
    int t = blockIdx.x * 256 + threadIdx.x;   // [0, 4096*1024)
    int i = t & 1023;
    int n = t >> 10;          // o*4+q
    int o = n >> 2, q = n & 3;
    // sign masks per q (bit c set => negative): q0:0xE q1:0x8 q2:0x2 q3:0x4
    unsigned packed = 0xEu | (0x8u << 4) | (0x2u << 8) | (0x4u << 12);
    unsigned sm = (packed >> (q * 4)) & 0xFu;
    h16x4 out;
#pragma unroll
    for (int c = 0; c < 4; ++c) {
        int d = q ^ c;
        float w = W[((long)d * EMB + o) * EMB + i];
        out[c] = (h16)(((sm >> c) & 1u) ? -w : w);
    }
    *(h16x4*)&M[(long)n * ED4 + i * 4] = out;
}

// ---------- fp32 -> fp16 convert (x inputs), 4 elems/thread ----------
__global__ __launch_bounds__(256) void k_f32_to_f16(const float* __restrict__ in, h16* __restrict__ out) {
    long i = ((long)blockIdx.x * 256 + threadIdx.x) * 4;
    float4 v = *(const float4*)(in + i);
    h16x4 o;
    o[0] = (h16)v.x; o[1] = (h16)v.y; o[2] = (h16)v.z; o[3] = (h16)v.w;
    *(h16x4*)(out + i) = o;
}

// =====================================================================
// 256x256-tile, BK=64, 2-phase GEMM — r16: exact r14 green kernel
// (BK=32 experiment reverted: grid=256 wg on 256 CUs means occupancy is
// grid-bound at 1 block/CU — smaller LDS cannot raise it; r15 regressed).
// Generalized (lda/ldb/ldc, alpha, zb/zh batch strides, optional bias):
// serves projections (nt=64), scores (nt=4, z=32), and NOW PV (nt=16,
// z=32, B = Vt rows=256 so by=0 only). Inner loop, swizzle, vmcnt
// ladder identical to r13/r14 green. C[m][n]=alpha*sum_k A[m][k]*B[n][k](+bias).
// VT=true: V-projection epilogue writes Vt[(b*16+h)][f][t] directly.
// =====================================================================
#define BAR() __builtin_amdgcn_s_barrier()
#define STAGE(matv, basev, row0v, ldv, tt, hh) do { \
    const h16* _src = (basev) + ((row0v) + (hh) * 128L) * (ldv) + (long)(tt) * 64 + scol; \
    h16* _dst = &lds[(((tt) & 1) << 15) + (matv) * 16384 + (hh) * 8192 + w * 512]; \
    gload_lds16(_src, _dst); \
    gload_lds16(_src + 64 * (long)(ldv), _dst + 4096); \
} while (0)
#define LDA_(mh, m, ks) (*(const h16x8*)&lds[cb + (mh) * 8192 + (wm * 64 + (m) * 16 + fr) * 64 + ((((ks) * 4 + kq) ^ fr7) << 3)])
#define LDB_(nh, n, ks) (*(const h16x8*)&lds[cb + 16384 + (nh) * 8192 + (wn * 32 + (n) * 16 + fr) * 64 + ((((ks) * 4 + kq) ^ fr7) << 3)])
#define MFMA_Q(MH, NH, BF) do { \
    __builtin_amdgcn_s_setprio(1); \
    _Pragma("unroll") \
    for (int m = 0; m < 4; ++m) \
        _Pragma("unroll") \
        for (int n = 0; n < 2; ++n) { \
            acc[MH][NH][m][n] = __builtin_amdgcn_mfma_f32_16x16x32_f16(af[m][0], BF[n][0], acc[MH][NH][m][n], 0, 0, 0); \
            acc[MH][NH][m][n] = __builtin_amdgcn_mfma_f32_16x16x32_f16(af[m][1], BF[n][1], acc[MH][NH][m][n], 0, 0, 0); \
        } \
    __builtin_amdgcn_s_setprio(0); \
} while (0)

template <typename OUT_T, bool VT, bool HAS_BIAS>
__global__ __launch_bounds__(512, 2) void k_gemm256(
    const h16* __restrict__ A, const h16* __restrict__ B,
    OUT_T* __restrict__ C, const float* __restrict__ bias,
    int lda, int ldb, int ldc,
    long sAb, long sAh, long sBb, long sBh, long sCb, long sCh,
    float alpha, int nt)
{
    __shared__ __align__(16) h16 lds[65536];   // 128 KiB

    const int tid = threadIdx.x;
    const int w  = tid >> 6, l = tid & 63;
    const int wm = w >> 2, wn = w & 3;          // wave grid 2x4 within each quadrant
    const int fr = l & 15, fr7 = l & 7, kq = l >> 4;

    const int z = blockIdx.z, zb = z >> 4, zh = z & 15;
    const h16* Ab = A + zb * sAb + zh * sAh;
    const h16* Bb = B + zb * sBb + zh * sBh;

    // staging: thread covers 16B; srow in [0,64) per gload, swizzled col
    const int srow = w * 8 + (l >> 3);
    const int scol = ((l & 7) ^ ((l >> 3) & 7)) << 3;
    const long arow0 = (long)blockIdx.x * 256 + srow;
    const long brow0 = (long)blockIdx.y * 256 + srow;

    f32x4 acc[2][2][4][2] = {};   // [mh][nh][m][n]

    // prologue: 0.A0 0.B0 0.A1 0.B1 1.A0 1.B0 (12 loads); vmcnt(4) -> tile0 landed
    STAGE(0, Ab, arow0, lda, 0, 0);
    STAGE(1, Bb, brow0, ldb, 0, 0);
    STAGE(0, Ab, arow0, lda, 0, 1);
    STAGE(1, Bb, brow0, ldb, 0, 1);
    STAGE(0, Ab, arow0, lda, 1, 0);
    STAGE(1, Bb, brow0, ldb, 1, 0);
    asm volatile("s_waitcnt vmcnt(4)" ::: "memory");
    __builtin_amdgcn_sched_barrier(0);
    BAR();

    for (int t = 0; t < nt; ++t) {
        const int cb = (t & 1) << 15;
        h16x8 af[4][2], b0[2][2], b1[2][2];

        // ---- phase A: quadrants (0,0)+(0,1) — read A0,B0,B1; stage (t+1).A1,B1 ----
#pragma unroll
        for (int m = 0; m < 4; ++m) { af[m][0] = LDA_(0, m, 0); af[m][1] = LDA_(0, m, 1); }
#pragma unroll
        for (int n = 0; n < 2; ++n) { b0[n][0] = LDB_(0, n, 0); b0[n][1] = LDB_(0, n, 1); }
#pragma unroll
        for (int n = 0; n < 2; ++n) { b1[n][0] = LDB_(1, n, 0); b1[n][1] = LDB_(1, n, 1); }
        if (t + 1 < nt) {
            STAGE(0, Ab, arow0, lda, t + 1, 1);
            STAGE(1, Bb, brow0, ldb, t + 1, 1);
        }
        MFMA_Q(0, 0, b0);
        MFMA_Q(0, 1, b1);
        BAR();

        // ---- phase B: quadrants (1,0)+(1,1) — read A1; stage (t+2).A0,B0; drain ----
#pragma unroll
        for (int m = 0; m < 4; ++m) { af[m][0] = LDA_(1, m, 0); af[m][1] = LDA_(1, m, 1); }
        if (t + 2 < nt) {
            STAGE(0, Ab, arow0, lda, t + 2, 0);
            STAGE(1, Bb, brow0, ldb, t + 2, 0);
        }
        if (t < nt - 2) { asm volatile("s_waitcnt vmcnt(4)" ::: "memory"); }
        else            { asm volatile("s_waitcnt vmcnt(0)" ::: "memory"); }
        __builtin_amdgcn_sched_barrier(0);
        MFMA_Q(1, 0, b0);
        MFMA_Q(1, 1, b1);
        BAR();
    }

    // epilogue: row = bx*256 + mh*128 + wm*64 + m*16 + kq*4 + j
    //           col = by*256 + nh*128 + wn*32 + n*16 + fr
    OUT_T* Cb = C + zb * sCb + zh * sCh;
    const long row00 = (long)blockIdx.x * 256 + wm * 64 + kq * 4;
    const int  col00 = (int)blockIdx.y * 256 + wn * 32 + fr;
#pragma unroll
    for (int mh = 0; mh < 2; ++mh)
#pragma unroll
        for (int nh = 0; nh < 2; ++nh)
#pragma unroll
            for (int n = 0; n < 2; ++n) {
                const int col = col00 + nh * 128 + n * 16;
                const float bv = HAS_BIAS ? bias[col] : 0.0f;
#pragma unroll
                for (int m = 0; m < 4; ++m) {
                    const long r0 = row00 + mh * 128 + m * 16;
                    if constexpr (VT) {
                        // Vt[(r>>10)*16 + (col>>8)][col&255][r&1023], r0 % 4 == 0
                        h16x4 o;
#pragma unroll
                        for (int j = 0; j < 4; ++j) o[j] = (h16)(acc[mh][nh][m][n][j] * alpha + bv);
                        const long zidx = (r0 >> 10) * 16 + (col >> 8);
                        *(h16x4*)((h16*)Cb + zidx * 262144L + (long)(col & 255) * 1024 + (r0 & 1023)) = o;
                    } else {
#pragma unroll
                        for (int j = 0; j < 4; ++j)
                            Cb[(r0 + j) * (long)ldc + col] = (OUT_T)(acc[mh][nh][m][n][j] * alpha + bv);
                    }
                }
            }
}

// ---------- row softmax over S[row][1024] fp16 in place ----------
__global__ __launch_bounds__(256) void k_softmax(h16* __restrict__ S) {
    const long row = blockIdx.x;
    h16* p = S + row * 1024;
    const int tid = threadIdx.x, w = tid >> 6, lane = tid & 63;
    h16x4 xi = *(const h16x4*)&p[tid * 4];
    float x[4];
#pragma unroll
    for (int j = 0; j < 4; ++j) x[j] = (float)xi[j];
    float m = fmaxf(fmaxf(x[0], x[1]), fmaxf(x[2], x[3]));
#pragma unroll
    for (int off = 32; off; off >>= 1) m = fmaxf(m, __shfl_xor(m, off));
    __shared__ float red[8];
    if (lane == 0) red[w] = m;
    __syncthreads();
    m = fmaxf(fmaxf(red[0], red[1]), fmaxf(red[2], red[3]));
    float s = 0.0f;
#pragma unroll
    for (int j = 0; j < 4; ++j) { x[j] = __expf(x[j] - m); s += x[j]; }
#pragma unroll
    for (int off = 32; off; off >>= 1) s += __shfl_xor(s, off);
    if (lane == 0) red[4 + w] = s;
    __syncthreads();
    s = red[4] + red[5] + red[6] + red[7];
    const float inv = 1.0f / s;
    h16x4 o;
#pragma unroll
    for (int j = 0; j < 4; ++j) o[j] = (h16)(x[j] * inv);
    *(h16x4*)&p[tid * 4] = o;
}

// ---------- launch ----------
extern "C" void kernel_launch(void* const* d_in, const int* in_sizes, int n_in,
                              void* d_out, int out_size, void* d_ws, size_t ws_size,
                              hipStream_t stream) {
    const float* q  = (const float*)d_in[0];
    const float* k  = (const float*)d_in[1];
    const float* v  = (const float*)d_in[2];
    const float* Wq = (const float*)d_in[3];
    const float* bq = (const float*)d_in[4];
    const float* Wk = (const float*)d_in[5];
    const float* bk = (const float*)d_in[6];
    const float* Wv = (const float*)d_in[7];
    const float* bv = (const float*)d_in[8];
    const float* Wo = (const float*)d_in[9];
    const float* bo = (const float*)d_in[10];
    float* out = (float*)d_out;

    // workspace: 256 MB exactly (proven budget; 320 MB faulted in r12).
    // Sc is 64 MB -> attention chunked as 2 x 32-z batches.
    char* ws = (char*)d_ws;
    const long MB = 1024L * 1024;
    h16* X  = (h16*)(ws + 0 * MB);     // 32 MB: converted q/k/v input (serial)
    h16* M  = (h16*)(ws + 32 * MB);    // 32 MB: effective weight (serial)
    h16* Qb = (h16*)(ws + 64 * MB);
    h16* Kb = (h16*)(ws + 96 * MB);
    h16* Vt = (h16*)(ws + 128 * MB);   // Vt[64 z][256 f][1024 t]
    h16* AO = (h16*)(ws + 160 * MB);
    h16* Sc = (h16*)(ws + 192 * MB);   // 64 MB score chunk (2 batches, 32 heads)

    dim3 blk(256);
    dim3 g256(16, 16, 1);

    // Q projection: convert, build weight, GEMM (serially reusing X, M)
    k_f32_to_f16<<<16384, blk, 0, stream>>>(q, X);
    k_build_m<<<16384, blk, 0, stream>>>(Wq, M);
    k_gemm256<h16, false, true><<<g256, 512, 0, stream>>>(
        X, M, Qb, bq, 4096, 4096, 4096, 0, 0, 0, 0, 0, 0, 1.0f, 64);

    // K projection
    k_f32_to_f16<<<16384, blk, 0, stream>>>(k, X);
    k_build_m<<<16384, blk, 0, stream>>>(Wk, M);
    k_gemm256<h16, false, true><<<g256, 512, 0, stream>>>(
        X, M, Kb, bk, 4096, 4096, 4096, 0, 0, 0, 0, 0, 0, 1.0f, 64);

    // V projection (epilogue writes transposed Vt directly)
    k_f32_to_f16<<<16384, blk, 0, stream>>>(v, X);
    k_build_m<<<16384, blk, 0, stream>>>(Wv, M);
    k_gemm256<h16, true, true><<<g256, 512, 0, stream>>>(
        X, M, Vt, bv, 4096, 4096, 4096, 0, 0, 0, 0, 0, 0, 1.0f, 64);

    // attention: 2 chunks of 32 z (= 2 batches x 16 heads) through 64 MB Sc
    for (int c = 0; c < 2; ++c) {
        const h16* Qc  = Qb + (long)c * 2 * 1024 * 4096;
        const h16* Kc  = Kb + (long)c * 2 * 1024 * 4096;
        const h16* VtC = Vt + (long)c * 32 * 262144;
        h16*       AOc = AO + (long)c * 2 * 1024 * 4096;

        // scores: Sc[z][1024][1024] = (Q K^T)/16, fp16 — 256^2-tile kernel, nt=4
        k_gemm256<h16, false, false><<<dim3(4, 4, 32), 512, 0, stream>>>(
            Qc, Kc, Sc, nullptr,
            4096, 4096, 1024,
            1024L * 4096, 256,                    // A: zb (batch), zh (head) strides
            1024L * 4096, 256,                    // B
            16L * 1024 * 1024, 1024L * 1024,      // C
            0.0625f, 4);

        // softmax rows in place (fp16): 32 z x 1024 rows
        k_softmax<<<32768, blk, 0, stream>>>(Sc);

        // attn out: AOc[t][h*256+f] = P_z . Vt_z^T — 256^2-tile kernel, nt=16
        k_gemm256<h16, false, false><<<dim3(4, 1, 32), 512, 0, stream>>>(
            Sc, VtC, AOc, nullptr,
            1024, 1024, 4096,
            16L * 1024 * 1024, 1024L * 1024,      // A: zb, zh strides (P)
            16L * 262144, 262144,                 // B: Vt
            1024L * 4096, 256,                    // C: AO
            1.0f, 16);
    }

    // output projection: out = AO . Mo^T + bo (fp32 out)
    k_build_m<<<16384, blk, 0, stream>>>(Wo, M);
    k_gemm256<float, false, true><<<g256, 512, 0, stream>>>(
        AO, M, out, bo, 4096, 4096, 4096, 0, 0, 0, 0, 0, 0, 1.0f, 64);
}